// Round 5
// baseline (326.121 us; speedup 1.0000x reference)
//
#include <hip/hip_runtime.h>
#include <hip/hip_bf16.h>
#include <math.h>

typedef __attribute__((ext_vector_type(8))) short bf16x8;
typedef __attribute__((ext_vector_type(4))) float f32x4;

#define D_EMBED 1024
#define SEQ 2048
#define NH 16
#define HD 64
// 0.125 * log2(e): folds the attention scale AND the exp->exp2 conversion into Q
#define QSCALE 0.1803368801111204f

__device__ __forceinline__ short f2bf(float f) {
    union { float f; unsigned u; } v; v.f = f;
    return (short)((v.u + 0x7FFFu + ((v.u >> 16) & 1u)) >> 16);
}

__device__ __forceinline__ unsigned pk_bf16(float a, float b) {
#if __has_builtin(__builtin_amdgcn_cvt_pk_bf16_f32)
    typedef __attribute__((ext_vector_type(2))) __bf16 vbf2;
    union { vbf2 v; unsigned u; } c;
    c.v = __builtin_amdgcn_cvt_pk_bf16_f32(a, b);
    return c.u;
#else
    return (unsigned)(unsigned short)f2bf(a) | ((unsigned)(unsigned short)f2bf(b) << 16);
#endif
}

__device__ __forceinline__ float bf2f_lo(unsigned u) {
    union { unsigned u; float f; } v; v.u = (u & 0xffffu) << 16; return v.f;
}
__device__ __forceinline__ float bf2f_hi(unsigned u) {
    union { unsigned u; float f; } v; v.u = u & 0xffff0000u; return v.f;
}

__device__ __forceinline__ float exp2f_(float x) {
#if __has_builtin(__builtin_amdgcn_exp2f)
    return __builtin_amdgcn_exp2f(x);
#else
    return __expf(x * 0.6931471805599453f);
#endif
}

typedef __attribute__((address_space(1))) const void gvoid_t;
typedef __attribute__((address_space(3))) void lvoid_t;
__device__ __forceinline__ void glds16(const void* g, void* l) {
    __builtin_amdgcn_global_load_lds((gvoid_t*)g, (lvoid_t*)l, 16, 0, 0);
}

// ---------- x fp32 -> bf16 ----------
__global__ __launch_bounds__(256) void xconv_kernel(const float* __restrict__ x,
                                                    short* __restrict__ xb)
{
    size_t i = ((size_t)blockIdx.x * 256 + threadIdx.x) * 8;
    float4 f0 = *(const float4*)(x + i);
    float4 f1 = *(const float4*)(x + i + 4);
    uint4 o;
    o.x = pk_bf16(f0.x, f0.y); o.y = pk_bf16(f0.z, f0.w);
    o.z = pk_bf16(f1.x, f1.y); o.w = pk_bf16(f1.z, f1.w);
    *(uint4*)(xb + i) = o;
}

// ---------- weight transpose + convert: Wt[z][n][k] = bf16(W[z][k][n]) ----------
__global__ __launch_bounds__(256) void wtrans_kernel(
    const float* __restrict__ w0, const float* __restrict__ w1,
    const float* __restrict__ w2, const float* __restrict__ w3,
    short* __restrict__ wt)
{
    __shared__ float tile[64][65];
    const float* W = (blockIdx.z == 0) ? w0 : (blockIdx.z == 1) ? w1
                   : (blockIdx.z == 2) ? w2 : w3;
    short* out = wt + (size_t)blockIdx.z * D_EMBED * D_EMBED;
    int k0 = blockIdx.x * 64, n0 = blockIdx.y * 64;
    #pragma unroll
    for (int i = 0; i < 16; i++) {
        int idx = threadIdx.x + i * 256; int r = idx >> 6, c = idx & 63;
        tile[r][c] = W[(size_t)(k0 + r) * D_EMBED + n0 + c];
    }
    __syncthreads();
    #pragma unroll
    for (int i = 0; i < 16; i++) {
        int idx = threadIdx.x + i * 256; int r = idx >> 6, c = idx & 63;
        out[(size_t)(n0 + r) * D_EMBED + k0 + c] = f2bf(tile[c][r]);
    }
}

// ---------- fused QKV GEMM (N=3072); Es unioned with As/Bs (dead after K-loop) ----------
__global__ __launch_bounds__(256) void gemm_qkv_kernel(
    const short* __restrict__ xb, const short* __restrict__ wt,
    const float* __restrict__ qb, const float* __restrict__ kb, const float* __restrict__ vb,
    short* __restrict__ qo, short* __restrict__ ko, short* __restrict__ vto)
{
    __shared__ __attribute__((aligned(16))) union ShQKV {
        struct { short As[128][32]; short Bs[128][32]; } ab;
        short Es[64][136];   // V-transpose staging [d][s], pad 8 — used only after K-loop
    } sh;
    const int tid = threadIdx.x;
    const int lane = tid & 63, wv = tid >> 6;
    const int l16 = lane & 15, quad = lane >> 4;
    const int wm = (wv & 1) * 64, wn = (wv >> 1) * 64;
    const int m0 = blockIdx.y * 128, n0 = blockIdx.x * 128;

    const short* aptr0 = xb + (size_t)(m0 + (tid >> 2)) * D_EMBED + (tid & 3) * 8;
    const short* aptr1 = aptr0 + (size_t)64 * D_EMBED;
    const short* bptr0 = wt + (size_t)(n0 + (tid >> 2)) * D_EMBED + (tid & 3) * 8;
    const short* bptr1 = bptr0 + (size_t)64 * D_EMBED;
    char* aldsb = (char*)&sh.ab.As[0][0] + wv * 1024;
    char* bldsb = (char*)&sh.ab.Bs[0][0] + wv * 1024;

    f32x4 acc[4][4];
    #pragma unroll
    for (int a = 0; a < 4; a++)
        #pragma unroll
        for (int b = 0; b < 4; b++) acc[a][b] = (f32x4){0.f, 0.f, 0.f, 0.f};

    for (int k0 = 0; k0 < D_EMBED; k0 += 32) {
        __syncthreads();
        glds16(aptr0 + k0, aldsb);
        glds16(aptr1 + k0, aldsb + 4096);
        glds16(bptr0 + k0, bldsb);
        glds16(bptr1 + k0, bldsb + 4096);
        __syncthreads();
        bf16x8 af[4], bfr[4];
        #pragma unroll
        for (int mi = 0; mi < 4; mi++) af[mi]  = *(const bf16x8*)&sh.ab.As[wm + mi * 16 + l16][quad * 8];
        #pragma unroll
        for (int ni = 0; ni < 4; ni++) bfr[ni] = *(const bf16x8*)&sh.ab.Bs[wn + ni * 16 + l16][quad * 8];
        #pragma unroll
        for (int mi = 0; mi < 4; mi++)
            #pragma unroll
            for (int ni = 0; ni < 4; ni++)
                acc[mi][ni] = __builtin_amdgcn_mfma_f32_16x16x32_bf16(af[mi], bfr[ni], acc[mi][ni], 0, 0, 0);
    }

    const int zz = n0 >> 10;                 // 0=q 1=k 2=v (uniform per block)
    if (zz == 2) {
        // V: transpose per head via LDS, then fully-coalesced b128 stores
        const int b = m0 >> 11, st0 = m0 & 2047;
        const int hbase = (n0 & 1023) >> 6;
        #pragma unroll
        for (int h2 = 0; h2 < 2; h2++) {
            __syncthreads();
            if ((wv >> 1) == h2) {
                #pragma unroll
                for (int mi = 0; mi < 4; mi++) {
                    int sbase = (wv & 1) * 64 + mi * 16 + quad * 4;
                    #pragma unroll
                    for (int ni = 0; ni < 4; ni++) {
                        int d = ni * 16 + l16;
                        float bv = vb[(n0 & 1023) + h2 * 64 + d];
                        uint2 pw;
                        pw.x = pk_bf16(acc[mi][ni][0] + bv, acc[mi][ni][1] + bv);
                        pw.y = pk_bf16(acc[mi][ni][2] + bv, acc[mi][ni][3] + bv);
                        *(uint2*)&sh.Es[d][sbase] = pw;
                    }
                }
            }
            __syncthreads();
            const int h = hbase + h2;
            #pragma unroll
            for (int j = 0; j < 4; j++) {
                int d = j * 16 + (tid >> 4);
                int sc = (tid & 15) * 8;
                bf16x8 vv = *(const bf16x8*)&sh.Es[d][sc];
                *(bf16x8*)(vto + ((size_t)(b * NH + h) * HD + d) * SEQ + st0 + sc) = vv;
            }
        }
    } else {
        const int ncol0 = (n0 & 1023) + wn;
        const float* bias = (zz == 0) ? qb : kb;
        #pragma unroll
        for (int mi = 0; mi < 4; mi++)
            #pragma unroll
            for (int ni = 0; ni < 4; ni++)
                #pragma unroll
                for (int rg = 0; rg < 4; rg++) {
                    int row = m0 + wm + mi * 16 + quad * 4 + rg;
                    int col = ncol0 + ni * 16 + l16;
                    float v = acc[mi][ni][rg] + bias[col];
                    int b = row >> 11, s = row & 2047, h = col >> 6, d = col & 63;
                    if (zz == 0) qo[(((size_t)(b * NH + h)) * SEQ + s) * HD + d] = f2bf(v * QSCALE);
                    else         ko[(((size_t)(b * NH + h)) * SEQ + s) * HD + d] = f2bf(v);
                }
    }
}

// ---------- flash attention: S^T layout, no-max softmax, 256 q/block, 64 q/wave ----------
// mode 0: full SEQ, write normalized attn. mode 1: K-split by blockIdx.z (ktn_base keys
// per split, last split truncated to SEQ), write raw O partial + l partial.
__global__ __launch_bounds__(256) void flash_kernel(
    const short* __restrict__ Q, const short* __restrict__ K,
    const short* __restrict__ Vt, short* __restrict__ attn,
    short* __restrict__ Op0, short* __restrict__ Op1, short* __restrict__ Op2,
    float* __restrict__ lp0, float* __restrict__ lp1, float* __restrict__ lp2,
    int ktn_base, int mode)
{
    __shared__ __attribute__((aligned(16))) short Ks[64][64];    // [key][d], 16B-group xor-swizzle by key&7
    __shared__ __attribute__((aligned(16))) short Vs[64][64];    // [d][key], 16B-group xor-swizzle by d&7
    __shared__ __attribute__((aligned(16))) short Ps[4][64][72]; // per-wave [q][key]
    const int bh = blockIdx.y, qt = blockIdx.x;
    const int kt0 = blockIdx.z * ktn_base;
    const int kn = min(ktn_base, SEQ - kt0);
    const int tid = threadIdx.x, lane = tid & 63, wv = tid >> 6;
    const int l16 = lane & 15, quad = lane >> 4;
    const int sw = l16 & 7;

    bf16x8 qf[4][2];
    #pragma unroll
    for (int g = 0; g < 4; g++) {
        const short* qp = Q + ((size_t)bh * SEQ + qt * 256 + wv * 64 + g * 16 + l16) * HD;
        qf[g][0] = *(const bf16x8*)(qp + quad * 8);
        qf[g][1] = *(const bf16x8*)(qp + 32 + quad * 8);
    }

    const int sr = tid >> 3;
    const int scg = (tid & 7) ^ (sr & 7);
    const short* kp0 = K  + ((size_t)bh * SEQ + sr) * HD + scg * 8;
    const short* vp0 = Vt + ((size_t)bh * HD + sr) * SEQ + scg * 8;
    char* kldsb = (char*)&Ks[0][0] + wv * 1024;
    char* vldsb = (char*)&Vs[0][0] + wv * 1024;

    float lsum[4] = {0.f, 0.f, 0.f, 0.f};
    f32x4 oacc[4][4];
    #pragma unroll
    for (int g = 0; g < 4; g++)
        #pragma unroll
        for (int di = 0; di < 4; di++) oacc[g][di] = (f32x4){0.f, 0.f, 0.f, 0.f};

    for (int kt = kt0; kt < kt0 + kn; kt += 64) {
        __syncthreads();
        glds16(kp0 + (size_t)kt * HD, kldsb);
        glds16(kp0 + (size_t)(kt + 32) * HD, kldsb + 4096);
        glds16(vp0 + kt, vldsb);
        glds16(vp0 + (size_t)32 * SEQ + kt, vldsb + 4096);
        __syncthreads();

        bf16x8 kf[4][2];
        #pragma unroll
        for (int ni = 0; ni < 4; ni++) {
            kf[ni][0] = *(const bf16x8*)&Ks[ni * 16 + l16][((quad    ) ^ sw) * 8];
            kf[ni][1] = *(const bf16x8*)&Ks[ni * 16 + l16][((quad + 4) ^ sw) * 8];
        }

        #pragma unroll
        for (int g = 0; g < 4; g++) {
            f32x4 sacc[4];
            #pragma unroll
            for (int ni = 0; ni < 4; ni++) {
                sacc[ni] = (f32x4){0.f, 0.f, 0.f, 0.f};
                sacc[ni] = __builtin_amdgcn_mfma_f32_16x16x32_bf16(kf[ni][0], qf[g][0], sacc[ni], 0, 0, 0);
                sacc[ni] = __builtin_amdgcn_mfma_f32_16x16x32_bf16(kf[ni][1], qf[g][1], sacc[ni], 0, 0, 0);
            }
            short* prow = &Ps[wv][g * 16 + l16][0];
            float ps = 0.f;
            #pragma unroll
            for (int ni = 0; ni < 4; ni++) {
                float p0 = exp2f_(sacc[ni][0]);
                float p1 = exp2f_(sacc[ni][1]);
                float p2 = exp2f_(sacc[ni][2]);
                float p3 = exp2f_(sacc[ni][3]);
                ps += (p0 + p1) + (p2 + p3);
                uint2 pw; pw.x = pk_bf16(p0, p1); pw.y = pk_bf16(p2, p3);
                *(uint2*)(prow + ni * 16 + quad * 4) = pw;
            }
            lsum[g] += ps;
        }

        bf16x8 vf[4][2];
        #pragma unroll
        for (int di = 0; di < 4; di++) {
            vf[di][0] = *(const bf16x8*)&Vs[di * 16 + l16][((quad    ) ^ sw) * 8];
            vf[di][1] = *(const bf16x8*)&Vs[di * 16 + l16][((quad + 4) ^ sw) * 8];
        }
        #pragma unroll
        for (int g = 0; g < 4; g++) {
            const short* prow = &Ps[wv][g * 16 + l16][0];
            bf16x8 pf0 = *(const bf16x8*)(prow + quad * 8);
            bf16x8 pf1 = *(const bf16x8*)(prow + 32 + quad * 8);
            #pragma unroll
            for (int di = 0; di < 4; di++) {
                oacc[g][di] = __builtin_amdgcn_mfma_f32_16x16x32_bf16(pf0, vf[di][0], oacc[g][di], 0, 0, 0);
                oacc[g][di] = __builtin_amdgcn_mfma_f32_16x16x32_bf16(pf1, vf[di][1], oacc[g][di], 0, 0, 0);
            }
        }
    }

    const int b = bh >> 4, h = bh & 15;
    short* Oz = (blockIdx.z == 0) ? Op0 : (blockIdx.z == 1) ? Op1 : Op2;
    float* lz = (blockIdx.z == 0) ? lp0 : (blockIdx.z == 1) ? lp1 : lp2;
    #pragma unroll
    for (int g = 0; g < 4; g++) {
        float l = lsum[g];
        l += __shfl_xor(l, 16);
        l += __shfl_xor(l, 32);
        if (mode) {
            if (quad == 0) lz[(size_t)bh * SEQ + qt * 256 + wv * 64 + g * 16 + l16] = l;
            #pragma unroll
            for (int di = 0; di < 4; di++)
                #pragma unroll
                for (int rg = 0; rg < 4; rg++) {
                    int s = qt * 256 + wv * 64 + g * 16 + quad * 4 + rg;
                    int col = h * HD + di * 16 + l16;
                    Oz[((size_t)b * SEQ + s) * D_EMBED + col] = f2bf(oacc[g][di][rg]);
                }
        } else {
            float rl[4];
            #pragma unroll
            for (int rg = 0; rg < 4; rg++) rl[rg] = 1.0f / __shfl(l, quad * 4 + rg);
            #pragma unroll
            for (int di = 0; di < 4; di++)
                #pragma unroll
                for (int rg = 0; rg < 4; rg++) {
                    int s = qt * 256 + wv * 64 + g * 16 + quad * 4 + rg;
                    int col = h * HD + di * 16 + l16;
                    attn[((size_t)b * SEQ + s) * D_EMBED + col] = f2bf(oacc[g][di][rg] * rl[rg]);
                }
        }
    }
}

// ---------- combine 2-way K-split partials ----------
__global__ __launch_bounds__(256) void combine2_kernel(
    const short* __restrict__ Op0, const short* __restrict__ Op1,
    const float* __restrict__ lp0, const float* __restrict__ lp1,
    short* __restrict__ attn)
{
    size_t i = (size_t)blockIdx.x * 256 + threadIdx.x;
    int r = (int)(i >> 7);
    int c8 = ((int)i & 127) * 8;
    int h = c8 >> 6, b = r >> 11, s = r & 2047;
    size_t li = (size_t)(b * NH + h) * SEQ + s;
    float rl = 1.0f / (lp0[li] + lp1[li]);
    uint4 a0 = *(const uint4*)(Op0 + i * 8);
    uint4 a1 = *(const uint4*)(Op1 + i * 8);
    unsigned ua[4] = {a0.x, a0.y, a0.z, a0.w};
    unsigned ub[4] = {a1.x, a1.y, a1.z, a1.w};
    uint4 o; unsigned uo[4];
    #pragma unroll
    for (int j = 0; j < 4; j++)
        uo[j] = pk_bf16((bf2f_lo(ua[j]) + bf2f_lo(ub[j])) * rl,
                        (bf2f_hi(ua[j]) + bf2f_hi(ub[j])) * rl);
    o.x = uo[0]; o.y = uo[1]; o.z = uo[2]; o.w = uo[3];
    *(uint4*)(attn + i * 8) = o;
}

// ---------- combine 3-way K-split partials ----------
__global__ __launch_bounds__(256) void combine3_kernel(
    const short* __restrict__ Op0, const short* __restrict__ Op1, const short* __restrict__ Op2,
    const float* __restrict__ lp0, const float* __restrict__ lp1, const float* __restrict__ lp2,
    short* __restrict__ attn)
{
    size_t i = (size_t)blockIdx.x * 256 + threadIdx.x;
    int r = (int)(i >> 7);
    int c8 = ((int)i & 127) * 8;
    int h = c8 >> 6, b = r >> 11, s = r & 2047;
    size_t li = (size_t)(b * NH + h) * SEQ + s;
    float rl = 1.0f / (lp0[li] + lp1[li] + lp2[li]);
    uint4 a0 = *(const uint4*)(Op0 + i * 8);
    uint4 a1 = *(const uint4*)(Op1 + i * 8);
    uint4 a2 = *(const uint4*)(Op2 + i * 8);
    unsigned ua[4] = {a0.x, a0.y, a0.z, a0.w};
    unsigned ub[4] = {a1.x, a1.y, a1.z, a1.w};
    unsigned uc[4] = {a2.x, a2.y, a2.z, a2.w};
    uint4 o; unsigned uo[4];
    #pragma unroll
    for (int j = 0; j < 4; j++)
        uo[j] = pk_bf16((bf2f_lo(ua[j]) + bf2f_lo(ub[j]) + bf2f_lo(uc[j])) * rl,
                        (bf2f_hi(ua[j]) + bf2f_hi(ub[j]) + bf2f_hi(uc[j])) * rl);
    o.x = uo[0]; o.y = uo[1]; o.z = uo[2]; o.w = uo[3];
    *(uint4*)(attn + i * 8) = o;
}

// ---------- output projection: out = attn @ o_w + o_b (fp32 out), 128x64 tiles ----------
__global__ __launch_bounds__(256) void gemm_out_kernel(
    const short* __restrict__ attn, const short* __restrict__ wt_o,
    const float* __restrict__ ob, float* __restrict__ out)
{
    __shared__ __attribute__((aligned(16))) short As[128][32];
    __shared__ __attribute__((aligned(16))) short Bs[64][32];
    const int tid = threadIdx.x;
    const int lane = tid & 63, wv = tid >> 6;
    const int l16 = lane & 15, quad = lane >> 4;
    const int wm = (wv & 1) * 64, wn = (wv >> 1) * 32;
    const int m0 = blockIdx.y * 128, n0 = blockIdx.x * 64;

    const short* aptr0 = attn + (size_t)(m0 + (tid >> 2)) * D_EMBED + (tid & 3) * 8;
    const short* aptr1 = aptr0 + (size_t)64 * D_EMBED;
    const short* bptr0 = wt_o + (size_t)(n0 + (tid >> 2)) * D_EMBED + (tid & 3) * 8;
    char* aldsb = (char*)&As[0][0] + wv * 1024;
    char* bldsb = (char*)&Bs[0][0] + wv * 1024;

    f32x4 acc[4][2];
    #pragma unroll
    for (int a = 0; a < 4; a++)
        #pragma unroll
        for (int b = 0; b < 2; b++) acc[a][b] = (f32x4){0.f, 0.f, 0.f, 0.f};

    for (int k0 = 0; k0 < D_EMBED; k0 += 32) {
        __syncthreads();
        glds16(aptr0 + k0, aldsb);
        glds16(aptr1 + k0, aldsb + 4096);
        glds16(bptr0 + k0, bldsb);
        __syncthreads();
        bf16x8 af[4], bfr[2];
        #pragma unroll
        for (int mi = 0; mi < 4; mi++) af[mi]  = *(const bf16x8*)&As[wm + mi * 16 + l16][quad * 8];
        #pragma unroll
        for (int ni = 0; ni < 2; ni++) bfr[ni] = *(const bf16x8*)&Bs[wn + ni * 16 + l16][quad * 8];
        #pragma unroll
        for (int mi = 0; mi < 4; mi++)
            #pragma unroll
            for (int ni = 0; ni < 2; ni++)
                acc[mi][ni] = __builtin_amdgcn_mfma_f32_16x16x32_bf16(af[mi], bfr[ni], acc[mi][ni], 0, 0, 0);
    }

    #pragma unroll
    for (int mi = 0; mi < 4; mi++)
        #pragma unroll
        for (int ni = 0; ni < 2; ni++)
            #pragma unroll
            for (int rg = 0; rg < 4; rg++) {
                int row = m0 + wm + mi * 16 + quad * 4 + rg;
                int col = n0 + wn + ni * 16 + l16;
                out[(size_t)row * D_EMBED + col] = acc[mi][ni][rg] + ob[col];
            }
}

extern "C" void kernel_launch(void* const* d_in, const int* in_sizes, int n_in,
                              void* d_out, int out_size, void* d_ws, size_t ws_size,
                              hipStream_t stream) {
    const float* x  = (const float*)d_in[0];
    const float* qw = (const float*)d_in[1];
    const float* qb = (const float*)d_in[2];
    const float* kw = (const float*)d_in[3];
    const float* kb = (const float*)d_in[4];
    const float* vw = (const float*)d_in[5];
    const float* vb = (const float*)d_in[6];
    const float* ow = (const float*)d_in[7];
    const float* ob = (const float*)d_in[8];

    char* ws = (char*)d_ws;
    short* xb  = (short*)(ws);                        // 16 MB
    short* wt  = (short*)(ws + (size_t)(16 << 20));   // 8 MB
    short* q   = (short*)(ws + (size_t)(24 << 20));   // 16 MB
    short* k   = (short*)(ws + (size_t)(40 << 20));   // 16 MB
    short* vt  = (short*)(ws + (size_t)(56 << 20));   // 16 MB (base total 72 MB)

    const bool split3 = ws_size >= (size_t)106 * 1024 * 1024;
    const bool split2 = !split3 && ws_size >= (size_t)105 * 1024 * 1024;
    short* Op0 = (short*)(ws + (size_t)(72 << 20));   // 16 MB
    short* Op1 = (short*)(ws + (size_t)(88 << 20));   // 16 MB
    short* Op2 = xb;                                  // 16 MB, aliases xb (dead after gemm_qkv)
    float* lp0 = (float*)(ws + (size_t)(104 << 20));  // 0.5 MB each
    float* lp1 = lp0 + (size_t)NH * 4 * SEQ;
    float* lp2 = lp1 + (size_t)NH * 4 * SEQ;

    xconv_kernel<<<4096, 256, 0, stream>>>(x, xb);
    wtrans_kernel<<<dim3(16, 16, 4), 256, 0, stream>>>(qw, kw, vw, ow, wt);
    gemm_qkv_kernel<<<dim3(24, 64), 256, 0, stream>>>(xb, wt, qb, kb, vb, q, k, vt);

    short* at;   // where the normalized attention output lands
    if (split3) {
        // grid 1536 = 2 clean residency generations at 3 blocks/CU
        at = q;  // q is dead after flash; combine writes into it
        flash_kernel<<<dim3(8, 64, 3), 256, 0, stream>>>(q, k, vt, (short*)nullptr,
                                                         Op0, Op1, Op2, lp0, lp1, lp2,
                                                         704, 1);
        combine3_kernel<<<(8192 * 1024 / 8) / 256, 256, 0, stream>>>(Op0, Op1, Op2,
                                                                     lp0, lp1, lp2, at);
    } else if (split2) {
        at = xb;
        flash_kernel<<<dim3(8, 64, 2), 256, 0, stream>>>(q, k, vt, (short*)nullptr,
                                                         Op0, Op1, Op1, lp0, lp1, lp1,
                                                         1024, 1);
        combine2_kernel<<<(8192 * 1024 / 8) / 256, 256, 0, stream>>>(Op0, Op1, lp0, lp1, at);
    } else {
        at = xb;
        flash_kernel<<<dim3(8, 64, 1), 256, 0, stream>>>(q, k, vt, at,
                                                         at, at, at, lp0, lp0, lp0,
                                                         SEQ, 0);
    }
    gemm_out_kernel<<<dim3(16, 64), 256, 0, stream>>>(at, wt + (size_t)3 * D_EMBED * D_EMBED, ob, (float*)d_out);
}

// Round 6
// 318.988 us; speedup vs baseline: 1.0224x; 1.0224x over previous
//
#include <hip/hip_runtime.h>
#include <hip/hip_bf16.h>
#include <math.h>

typedef __attribute__((ext_vector_type(8))) short bf16x8;
typedef __attribute__((ext_vector_type(4))) float f32x4;

#define D_EMBED 1024
#define SEQ 2048
#define NH 16
#define HD 64
// 0.125 * log2(e): folds the attention scale AND the exp->exp2 conversion into Q
#define QSCALE 0.1803368801111204f

__device__ __forceinline__ short f2bf(float f) {
    union { float f; unsigned u; } v; v.f = f;
    return (short)((v.u + 0x7FFFu + ((v.u >> 16) & 1u)) >> 16);
}

__device__ __forceinline__ unsigned pk_bf16(float a, float b) {
#if __has_builtin(__builtin_amdgcn_cvt_pk_bf16_f32)
    typedef __attribute__((ext_vector_type(2))) __bf16 vbf2;
    union { vbf2 v; unsigned u; } c;
    c.v = __builtin_amdgcn_cvt_pk_bf16_f32(a, b);
    return c.u;
#else
    return (unsigned)(unsigned short)f2bf(a) | ((unsigned)(unsigned short)f2bf(b) << 16);
#endif
}

__device__ __forceinline__ float exp2f_(float x) {
#if __has_builtin(__builtin_amdgcn_exp2f)
    return __builtin_amdgcn_exp2f(x);
#else
    return __expf(x * 0.6931471805599453f);
#endif
}

typedef __attribute__((address_space(1))) const void gvoid_t;
typedef __attribute__((address_space(3))) void lvoid_t;
__device__ __forceinline__ void glds16(const void* g, void* l) {
    __builtin_amdgcn_global_load_lds((gvoid_t*)g, (lvoid_t*)l, 16, 0, 0);
}

// ---------- fused prep: blocks 0..1023 = weight transpose, 1024..5119 = x fp32->bf16 ----------
__global__ __launch_bounds__(256) void prep_kernel(
    const float* __restrict__ x,
    const float* __restrict__ w0, const float* __restrict__ w1,
    const float* __restrict__ w2, const float* __restrict__ w3,
    short* __restrict__ wt, short* __restrict__ xb)
{
    __shared__ float tile[64][65];
    const int bid = blockIdx.x;
    if (bid < 1024) {
        const int z = bid >> 8, rem = bid & 255;
        const float* W = (z == 0) ? w0 : (z == 1) ? w1 : (z == 2) ? w2 : w3;
        short* out = wt + (size_t)z * D_EMBED * D_EMBED;
        int k0 = (rem & 15) * 64, n0 = (rem >> 4) * 64;
        #pragma unroll
        for (int i = 0; i < 16; i++) {
            int idx = threadIdx.x + i * 256; int r = idx >> 6, c = idx & 63;
            tile[r][c] = W[(size_t)(k0 + r) * D_EMBED + n0 + c];
        }
        __syncthreads();
        #pragma unroll
        for (int i = 0; i < 16; i++) {
            int idx = threadIdx.x + i * 256; int r = idx >> 6, c = idx & 63;
            out[(size_t)(n0 + r) * D_EMBED + k0 + c] = f2bf(tile[c][r]);
        }
    } else {
        size_t i = ((size_t)(bid - 1024) * 256 + threadIdx.x) * 8;
        float4 f0 = *(const float4*)(x + i);
        float4 f1 = *(const float4*)(x + i + 4);
        uint4 o;
        o.x = pk_bf16(f0.x, f0.y); o.y = pk_bf16(f0.z, f0.w);
        o.z = pk_bf16(f1.x, f1.y); o.w = pk_bf16(f1.z, f1.w);
        *(uint4*)(xb + i) = o;
    }
}

// ---------- fused QKV GEMM (N=3072); Es unioned with As/Bs (dead after K-loop) ----------
__global__ __launch_bounds__(256) void gemm_qkv_kernel(
    const short* __restrict__ xb, const short* __restrict__ wt,
    const float* __restrict__ qb, const float* __restrict__ kb, const float* __restrict__ vb,
    short* __restrict__ qo, short* __restrict__ ko, short* __restrict__ vto)
{
    __shared__ __attribute__((aligned(16))) union ShQKV {
        struct { short As[128][32]; short Bs[128][32]; } ab;
        short Es[64][136];   // V-transpose staging [d][s], pad 8 — used only after K-loop
    } sh;
    const int tid = threadIdx.x;
    const int lane = tid & 63, wv = tid >> 6;
    const int l16 = lane & 15, quad = lane >> 4;
    const int wm = (wv & 1) * 64, wn = (wv >> 1) * 64;
    const int m0 = blockIdx.y * 128, n0 = blockIdx.x * 128;

    const short* aptr0 = xb + (size_t)(m0 + (tid >> 2)) * D_EMBED + (tid & 3) * 8;
    const short* aptr1 = aptr0 + (size_t)64 * D_EMBED;
    const short* bptr0 = wt + (size_t)(n0 + (tid >> 2)) * D_EMBED + (tid & 3) * 8;
    const short* bptr1 = bptr0 + (size_t)64 * D_EMBED;
    char* aldsb = (char*)&sh.ab.As[0][0] + wv * 1024;
    char* bldsb = (char*)&sh.ab.Bs[0][0] + wv * 1024;

    f32x4 acc[4][4];
    #pragma unroll
    for (int a = 0; a < 4; a++)
        #pragma unroll
        for (int b = 0; b < 4; b++) acc[a][b] = (f32x4){0.f, 0.f, 0.f, 0.f};

    for (int k0 = 0; k0 < D_EMBED; k0 += 32) {
        __syncthreads();
        glds16(aptr0 + k0, aldsb);
        glds16(aptr1 + k0, aldsb + 4096);
        glds16(bptr0 + k0, bldsb);
        glds16(bptr1 + k0, bldsb + 4096);
        __syncthreads();
        bf16x8 af[4], bfr[4];
        #pragma unroll
        for (int mi = 0; mi < 4; mi++) af[mi]  = *(const bf16x8*)&sh.ab.As[wm + mi * 16 + l16][quad * 8];
        #pragma unroll
        for (int ni = 0; ni < 4; ni++) bfr[ni] = *(const bf16x8*)&sh.ab.Bs[wn + ni * 16 + l16][quad * 8];
        #pragma unroll
        for (int mi = 0; mi < 4; mi++)
            #pragma unroll
            for (int ni = 0; ni < 4; ni++)
                acc[mi][ni] = __builtin_amdgcn_mfma_f32_16x16x32_bf16(af[mi], bfr[ni], acc[mi][ni], 0, 0, 0);
    }

    const int zz = n0 >> 10;                 // 0=q 1=k 2=v (uniform per block)
    if (zz == 2) {
        // V: transpose per head via LDS, then fully-coalesced b128 stores
        const int b = m0 >> 11, st0 = m0 & 2047;
        const int hbase = (n0 & 1023) >> 6;
        #pragma unroll
        for (int h2 = 0; h2 < 2; h2++) {
            __syncthreads();
            if ((wv >> 1) == h2) {
                #pragma unroll
                for (int mi = 0; mi < 4; mi++) {
                    int sbase = (wv & 1) * 64 + mi * 16 + quad * 4;
                    #pragma unroll
                    for (int ni = 0; ni < 4; ni++) {
                        int d = ni * 16 + l16;
                        float bv = vb[(n0 & 1023) + h2 * 64 + d];
                        uint2 pw;
                        pw.x = pk_bf16(acc[mi][ni][0] + bv, acc[mi][ni][1] + bv);
                        pw.y = pk_bf16(acc[mi][ni][2] + bv, acc[mi][ni][3] + bv);
                        *(uint2*)&sh.Es[d][sbase] = pw;
                    }
                }
            }
            __syncthreads();
            const int h = hbase + h2;
            #pragma unroll
            for (int j = 0; j < 4; j++) {
                int d = j * 16 + (tid >> 4);
                int sc = (tid & 15) * 8;
                bf16x8 vv = *(const bf16x8*)&sh.Es[d][sc];
                *(bf16x8*)(vto + ((size_t)(b * NH + h) * HD + d) * SEQ + st0 + sc) = vv;
            }
        }
    } else {
        const int ncol0 = (n0 & 1023) + wn;
        const float* bias = (zz == 0) ? qb : kb;
        #pragma unroll
        for (int mi = 0; mi < 4; mi++)
            #pragma unroll
            for (int ni = 0; ni < 4; ni++)
                #pragma unroll
                for (int rg = 0; rg < 4; rg++) {
                    int row = m0 + wm + mi * 16 + quad * 4 + rg;
                    int col = ncol0 + ni * 16 + l16;
                    float v = acc[mi][ni][rg] + bias[col];
                    int b = row >> 11, s = row & 2047, h = col >> 6, d = col & 63;
                    if (zz == 0) qo[(((size_t)(b * NH + h)) * SEQ + s) * HD + d] = f2bf(v * QSCALE);
                    else         ko[(((size_t)(b * NH + h)) * SEQ + s) * HD + d] = f2bf(v);
                }
    }
}

// ---------- flash attention: S^T layout, no-max softmax, 256 q/block, 64 q/wave ----------
// K fragments loaded directly from global (L1-resident tile); only V + P go through LDS.
// V DMA issues before pass-1 so staging hides under QK/exp compute.
__global__ __launch_bounds__(256) void flash_kernel(
    const short* __restrict__ Q, const short* __restrict__ K,
    const short* __restrict__ Vt, short* __restrict__ attn)
{
    __shared__ __attribute__((aligned(16))) short Vs[64][64];    // [d][key], 16B-group xor-swizzle by d&7
    __shared__ __attribute__((aligned(16))) short Ps[4][64][72]; // per-wave [q][key]
    const int bh = blockIdx.y, qt = blockIdx.x;
    const int tid = threadIdx.x, lane = tid & 63, wv = tid >> 6;
    const int l16 = lane & 15, quad = lane >> 4;
    const int sw = l16 & 7;

    // Q fragments (B-operand: col = query l16), four 16-query groups per wave
    bf16x8 qf[4][2];
    #pragma unroll
    for (int g = 0; g < 4; g++) {
        const short* qp = Q + ((size_t)bh * SEQ + qt * 256 + wv * 64 + g * 16 + l16) * HD;
        qf[g][0] = *(const bf16x8*)(qp + quad * 8);
        qf[g][1] = *(const bf16x8*)(qp + 32 + quad * 8);
    }

    // V staging: thread t -> row (t>>3)+{0,32}, 16B col-group (t&7)^(row&7)
    const int sr = tid >> 3;
    const int scg = (tid & 7) ^ (sr & 7);
    const short* vp0 = Vt + ((size_t)bh * HD + sr) * SEQ + scg * 8;
    char* vldsb = (char*)&Vs[0][0] + wv * 1024;

    // K A-fragment global base: row = key (l16 within 16-key group), 16B chunk quad*8
    const short* kb0 = K + ((size_t)bh * SEQ + l16) * HD + quad * 8;

    float lsum[4] = {0.f, 0.f, 0.f, 0.f};
    f32x4 oacc[4][4];
    #pragma unroll
    for (int g = 0; g < 4; g++)
        #pragma unroll
        for (int di = 0; di < 4; di++) oacc[g][di] = (f32x4){0.f, 0.f, 0.f, 0.f};

    for (int kt = 0; kt < SEQ; kt += 64) {
        __syncthreads();   // Vs of previous tile fully consumed by all waves
        glds16(vp0 + kt, vldsb);
        glds16(vp0 + (size_t)32 * SEQ + kt, vldsb + 4096);

        // K fragments straight from global (no LDS round-trip)
        bf16x8 kf[4][2];
        #pragma unroll
        for (int ni = 0; ni < 4; ni++) {
            const short* kp = kb0 + (size_t)(kt + ni * 16) * HD;
            kf[ni][0] = *(const bf16x8*)kp;
            kf[ni][1] = *(const bf16x8*)(kp + 32);
        }

        // pass 1: S^T = K·Q^T, exp2 (fixed max), pack P rows (wave-private)
        #pragma unroll
        for (int g = 0; g < 4; g++) {
            f32x4 sacc[4];
            #pragma unroll
            for (int ni = 0; ni < 4; ni++) {
                sacc[ni] = (f32x4){0.f, 0.f, 0.f, 0.f};
                sacc[ni] = __builtin_amdgcn_mfma_f32_16x16x32_bf16(kf[ni][0], qf[g][0], sacc[ni], 0, 0, 0);
                sacc[ni] = __builtin_amdgcn_mfma_f32_16x16x32_bf16(kf[ni][1], qf[g][1], sacc[ni], 0, 0, 0);
            }
            short* prow = &Ps[wv][g * 16 + l16][0];
            float ps = 0.f;
            #pragma unroll
            for (int ni = 0; ni < 4; ni++) {
                float p0 = exp2f_(sacc[ni][0]);
                float p1 = exp2f_(sacc[ni][1]);
                float p2 = exp2f_(sacc[ni][2]);
                float p3 = exp2f_(sacc[ni][3]);
                ps += (p0 + p1) + (p2 + p3);
                uint2 pw; pw.x = pk_bf16(p0, p1); pw.y = pk_bf16(p2, p3);
                *(uint2*)(prow + ni * 16 + quad * 4) = pw;
            }
            lsum[g] += ps;
        }

        __syncthreads();   // V DMA complete (vmcnt drains at barrier)

        // pass 2: O += P·V
        bf16x8 vf[4][2];
        #pragma unroll
        for (int di = 0; di < 4; di++) {
            vf[di][0] = *(const bf16x8*)&Vs[di * 16 + l16][((quad    ) ^ sw) * 8];
            vf[di][1] = *(const bf16x8*)&Vs[di * 16 + l16][((quad + 4) ^ sw) * 8];
        }
        #pragma unroll
        for (int g = 0; g < 4; g++) {
            const short* prow = &Ps[wv][g * 16 + l16][0];
            bf16x8 pf0 = *(const bf16x8*)(prow + quad * 8);
            bf16x8 pf1 = *(const bf16x8*)(prow + 32 + quad * 8);
            #pragma unroll
            for (int di = 0; di < 4; di++) {
                oacc[g][di] = __builtin_amdgcn_mfma_f32_16x16x32_bf16(pf0, vf[di][0], oacc[g][di], 0, 0, 0);
                oacc[g][di] = __builtin_amdgcn_mfma_f32_16x16x32_bf16(pf1, vf[di][1], oacc[g][di], 0, 0, 0);
            }
        }
    }

    // epilogue: reduce l across quads (2 shuffles), normalize, store
    const int b = bh >> 4, h = bh & 15;
    #pragma unroll
    for (int g = 0; g < 4; g++) {
        float l = lsum[g];
        l += __shfl_xor(l, 16);
        l += __shfl_xor(l, 32);          // every lane: full sum for query l16 of group g
        float rl[4];
        #pragma unroll
        for (int rg = 0; rg < 4; rg++) rl[rg] = 1.0f / __shfl(l, quad * 4 + rg);
        #pragma unroll
        for (int di = 0; di < 4; di++)
            #pragma unroll
            for (int rg = 0; rg < 4; rg++) {
                int s = qt * 256 + wv * 64 + g * 16 + quad * 4 + rg;
                int col = h * HD + di * 16 + l16;
                attn[((size_t)b * SEQ + s) * D_EMBED + col] = f2bf(oacc[g][di][rg] * rl[rg]);
            }
    }
}

// ---------- output projection: out = attn @ o_w + o_b (fp32 out), 128x64 tiles ----------
__global__ __launch_bounds__(256) void gemm_out_kernel(
    const short* __restrict__ attn, const short* __restrict__ wt_o,
    const float* __restrict__ ob, float* __restrict__ out)
{
    __shared__ __attribute__((aligned(16))) short As[128][32];
    __shared__ __attribute__((aligned(16))) short Bs[64][32];
    const int tid = threadIdx.x;
    const int lane = tid & 63, wv = tid >> 6;
    const int l16 = lane & 15, quad = lane >> 4;
    const int wm = (wv & 1) * 64, wn = (wv >> 1) * 32;
    const int m0 = blockIdx.y * 128, n0 = blockIdx.x * 64;

    const short* aptr0 = attn + (size_t)(m0 + (tid >> 2)) * D_EMBED + (tid & 3) * 8;
    const short* aptr1 = aptr0 + (size_t)64 * D_EMBED;
    const short* bptr0 = wt_o + (size_t)(n0 + (tid >> 2)) * D_EMBED + (tid & 3) * 8;
    char* aldsb = (char*)&As[0][0] + wv * 1024;
    char* bldsb = (char*)&Bs[0][0] + wv * 1024;

    f32x4 acc[4][2];
    #pragma unroll
    for (int a = 0; a < 4; a++)
        #pragma unroll
        for (int b = 0; b < 2; b++) acc[a][b] = (f32x4){0.f, 0.f, 0.f, 0.f};

    for (int k0 = 0; k0 < D_EMBED; k0 += 32) {
        __syncthreads();
        glds16(aptr0 + k0, aldsb);
        glds16(aptr1 + k0, aldsb + 4096);
        glds16(bptr0 + k0, bldsb);
        __syncthreads();
        bf16x8 af[4], bfr[2];
        #pragma unroll
        for (int mi = 0; mi < 4; mi++) af[mi]  = *(const bf16x8*)&As[wm + mi * 16 + l16][quad * 8];
        #pragma unroll
        for (int ni = 0; ni < 2; ni++) bfr[ni] = *(const bf16x8*)&Bs[wn + ni * 16 + l16][quad * 8];
        #pragma unroll
        for (int mi = 0; mi < 4; mi++)
            #pragma unroll
            for (int ni = 0; ni < 2; ni++)
                acc[mi][ni] = __builtin_amdgcn_mfma_f32_16x16x32_bf16(af[mi], bfr[ni], acc[mi][ni], 0, 0, 0);
    }

    #pragma unroll
    for (int mi = 0; mi < 4; mi++)
        #pragma unroll
        for (int ni = 0; ni < 2; ni++)
            #pragma unroll
            for (int rg = 0; rg < 4; rg++) {
                int row = m0 + wm + mi * 16 + quad * 4 + rg;
                int col = n0 + wn + ni * 16 + l16;
                out[(size_t)row * D_EMBED + col] = acc[mi][ni][rg] + ob[col];
            }
}

extern "C" void kernel_launch(void* const* d_in, const int* in_sizes, int n_in,
                              void* d_out, int out_size, void* d_ws, size_t ws_size,
                              hipStream_t stream) {
    const float* x  = (const float*)d_in[0];
    const float* qw = (const float*)d_in[1];
    const float* qb = (const float*)d_in[2];
    const float* kw = (const float*)d_in[3];
    const float* kb = (const float*)d_in[4];
    const float* vw = (const float*)d_in[5];
    const float* vb = (const float*)d_in[6];
    const float* ow = (const float*)d_in[7];
    const float* ob = (const float*)d_in[8];

    char* ws = (char*)d_ws;
    short* xb  = (short*)(ws);                        // 16 MB, reused as `at` after gemm_qkv
    short* wt  = (short*)(ws + (size_t)(16 << 20));   // 8 MB (q,k,v,o transposed bf16)
    short* q   = (short*)(ws + (size_t)(24 << 20));   // 16 MB
    short* k   = (short*)(ws + (size_t)(40 << 20));   // 16 MB
    short* vt  = (short*)(ws + (size_t)(56 << 20));   // 16 MB (total 72 MB)
    short* at  = xb;

    prep_kernel<<<5120, 256, 0, stream>>>(x, qw, kw, vw, ow, wt, xb);
    gemm_qkv_kernel<<<dim3(24, 64), 256, 0, stream>>>(xb, wt, qb, kb, vb, q, k, vt);
    flash_kernel<<<dim3(8, 64), 256, 0, stream>>>(q, k, vt, at);
    gemm_out_kernel<<<dim3(16, 64), 256, 0, stream>>>(at, wt + (size_t)3 * D_EMBED * D_EMBED, ob, (float*)d_out);
}